// Round 7
// baseline (138.352 us; speedup 1.0000x reference)
//
#include <hip/hip_runtime.h>

#define EPSN 1e-12f
#define MOM 0.9f
#define MAXC 1024   // C=1000 fits
#define CAP 8192    // per-class bucket capacity (true max ~1150 for this input)
#define SWIN 4096   // rows per scatter block
#define HSPLIT 4    // class_reduce blocks per class

typedef float floatx4 __attribute__((ext_vector_type(4)));

// ---------------- K1: fused scatter (count -> reserve -> rank+write) -------
// Bucketed layout idx[c*CAP + pos]; cursor[c] ends equal to the class count.
__global__ __launch_bounds__(1024) void scatter_kernel(
    const int* __restrict__ labels, int N, int C, int* __restrict__ cursor,
    int* __restrict__ idx) {
  __shared__ int llab[SWIN];    // window labels (read labels once)
  __shared__ int lcnt[MAXC];    // per-block class count, then rank counter
  __shared__ int lbase[MAXC];   // reserved global base per class
  const int s = blockIdx.x * SWIN;
  const int e = min(s + SWIN, N);
  const int nw = e - s;

  for (int i = threadIdx.x; i < C; i += blockDim.x) { lcnt[i] = 0; }
  __syncthreads();
  for (int i = threadIdx.x; i < nw; i += blockDim.x) {
    const int lab = labels[s + i];
    llab[i] = lab;
    atomicAdd(&lcnt[lab], 1);
  }
  __syncthreads();
  for (int i = threadIdx.x; i < C; i += blockDim.x) {
    const int k = lcnt[i];
    lbase[i] = k ? atomicAdd(&cursor[i], k) : 0;
    lcnt[i] = 0;   // reuse as rank counter
  }
  __syncthreads();
  for (int i = threadIdx.x; i < nw; i += blockDim.x) {
    const int lab = llab[i];
    const int r = atomicAdd(&lcnt[lab], 1);
    __builtin_nontemporal_store(s + i, &idx[lab * CAP + lbase[lab] + r]);
  }
}

// ---------------- K2: per-class gather + normalize + reduce ----------------
// HSPLIT blocks per class (one per quarter), 4 waves per block. Row layout:
// 16 lanes x float8 -> 4 rows per wave-instruction; one 4-level shuffle
// round reduces 4 row-norms at once. Unmasked main loop + masked tail.
__global__ __launch_bounds__(256) void class_reduce_kernel(
    const float* __restrict__ feat, const int* __restrict__ idx,
    const int* __restrict__ cnt, float* __restrict__ segp, int C) {
  __shared__ float part[4][128];
  const int c = blockIdx.x >> 2;
  const int h = blockIdx.x & 3;
  const int w = threadIdx.x >> 6;
  const int lane = threadIdx.x & 63;
  const int g = lane >> 4;     // row-group within wave (0..3)
  const int k = lane & 15;     // lane within group -> cols k*8..k*8+7
  const int n = cnt[c];
  const int per = (n + HSPLIT - 1) / HSPLIT;
  const int start = h * per;
  const int nh = max(0, min(per, n - start));
  const int beg = c * CAP + start;

  float acc[8];
  #pragma unroll
  for (int j = 0; j < 8; ++j) acc[j] = 0.f;

  const float* fbase = feat + (size_t)k * 8;
  const int tid16 = w * 4 + g;   // 0..15

  int base = 0;
  // ---- main loop: all 64 rows of the window valid, no masks ----
  for (; base + 63 < nh; base += 64) {
    const int j0 = base + tid16;
    int ri[4];
    #pragma unroll
    for (int u = 0; u < 4; ++u) ri[u] = idx[beg + j0 + u * 16];
    floatx4 a[4], b[4];
    #pragma unroll
    for (int u = 0; u < 4; ++u) {
      const float* p = fbase + (size_t)ri[u] * 128;
      a[u] = __builtin_nontemporal_load(reinterpret_cast<const floatx4*>(p));
      b[u] = __builtin_nontemporal_load(reinterpret_cast<const floatx4*>(p) + 1);
    }
    float sq[4];
    #pragma unroll
    for (int u = 0; u < 4; ++u) {
      sq[u] = a[u].x * a[u].x + a[u].y * a[u].y + a[u].z * a[u].z + a[u].w * a[u].w +
              b[u].x * b[u].x + b[u].y * b[u].y + b[u].z * b[u].z + b[u].w * b[u].w;
    }
    #pragma unroll
    for (int m = 1; m <= 8; m <<= 1) {
      #pragma unroll
      for (int u = 0; u < 4; ++u) sq[u] += __shfl_xor(sq[u], m);
    }
    #pragma unroll
    for (int u = 0; u < 4; ++u) {
      const float inv = 1.0f / fmaxf(sqrtf(sq[u]), EPSN);
      acc[0] += a[u].x * inv; acc[1] += a[u].y * inv;
      acc[2] += a[u].z * inv; acc[3] += a[u].w * inv;
      acc[4] += b[u].x * inv; acc[5] += b[u].y * inv;
      acc[6] += b[u].z * inv; acc[7] += b[u].w * inv;
    }
  }
  // ---- masked tail (at most one iteration) ----
  if (base < nh) {
    const int j0 = base + tid16;
    bool vm[4]; int ri[4];
    #pragma unroll
    for (int u = 0; u < 4; ++u) {
      const int jj = j0 + u * 16;
      vm[u] = jj < nh;
      ri[u] = idx[beg + (vm[u] ? jj : base)];
    }
    floatx4 a[4], b[4];
    #pragma unroll
    for (int u = 0; u < 4; ++u) {
      const float* p = fbase + (size_t)ri[u] * 128;
      a[u] = __builtin_nontemporal_load(reinterpret_cast<const floatx4*>(p));
      b[u] = __builtin_nontemporal_load(reinterpret_cast<const floatx4*>(p) + 1);
      if (!vm[u]) { a[u] = (floatx4)(0.f); b[u] = (floatx4)(0.f); }
    }
    float sq[4];
    #pragma unroll
    for (int u = 0; u < 4; ++u) {
      sq[u] = a[u].x * a[u].x + a[u].y * a[u].y + a[u].z * a[u].z + a[u].w * a[u].w +
              b[u].x * b[u].x + b[u].y * b[u].y + b[u].z * b[u].z + b[u].w * b[u].w;
    }
    #pragma unroll
    for (int m = 1; m <= 8; m <<= 1) {
      #pragma unroll
      for (int u = 0; u < 4; ++u) sq[u] += __shfl_xor(sq[u], m);
    }
    #pragma unroll
    for (int u = 0; u < 4; ++u) {
      const float inv = 1.0f / fmaxf(sqrtf(sq[u]), EPSN);
      acc[0] += a[u].x * inv; acc[1] += a[u].y * inv;
      acc[2] += a[u].z * inv; acc[3] += a[u].w * inv;
      acc[4] += b[u].x * inv; acc[5] += b[u].y * inv;
      acc[6] += b[u].z * inv; acc[7] += b[u].w * inv;
    }
  }

  // combine the 4 row-groups (they accumulate the same 128 columns)
  #pragma unroll
  for (int j = 0; j < 8; ++j) {
    acc[j] += __shfl_xor(acc[j], 16);
    acc[j] += __shfl_xor(acc[j], 32);
  }
  if (g == 0) {
    #pragma unroll
    for (int j = 0; j < 8; ++j) part[w][k * 8 + j] = acc[j];
  }
  __syncthreads();
  if (threadIdx.x < 128) {
    const float sTot = part[0][threadIdx.x] + part[1][threadIdx.x] +
                       part[2][threadIdx.x] + part[3][threadIdx.x];
    segp[((size_t)h * C + c) * 128 + threadIdx.x] = sTot;
  }
}

// ---------------- K3: finalize (wave per class) ----------------------------
__global__ __launch_bounds__(256) void finalize_kernel(
    const float* __restrict__ segp, const int* __restrict__ cnt,
    const float* __restrict__ proto, float* __restrict__ out, int C) {
  int wid = threadIdx.x >> 6;
  int lane = threadIdx.x & 63;
  int c = blockIdx.x * (blockDim.x >> 6) + wid;
  if (c >= C) return;

  const float n = (float)cnt[c];
  float sx = 0.f, sy = 0.f;
  #pragma unroll
  for (int h = 0; h < HSPLIT; ++h) {
    const float2 s0 = *reinterpret_cast<const float2*>(
        segp + ((size_t)h * C + c) * 128 + lane * 2);
    sx += s0.x; sy += s0.y;
  }
  const float2 p = *reinterpret_cast<const float2*>(proto + (size_t)c * 128 + lane * 2);

  const float inv_c = 1.0f / fmaxf(n, 1.0f);
  const float mx = sx * inv_c, my = sy * inv_c;

  float ss = mx * mx + my * my;   // for l2norm(feat_mean)
  float ps = p.x + p.y;           // elementwise sum of prototype row
  #pragma unroll
  for (int m = 32; m > 0; m >>= 1) {
    ss += __shfl_xor(ss, m);
    ps += __shfl_xor(ps, m);
  }
  const float fnorm = fmaxf(sqrtf(ss), EPSN);
  const float fx = mx / fnorm, fy = my / fnorm;

  const float ex = MOM * p.x + (1.0f - MOM) * fx;
  const float ey = MOM * p.y + (1.0f - MOM) * fy;
  float es = ex * ex + ey * ey;
  #pragma unroll
  for (int m = 32; m > 0; m >>= 1) es += __shfl_xor(es, m);
  const float en = fmaxf(sqrtf(es), EPSN);

  const bool proto_zero = (ps == 0.0f);
  float ox = proto_zero ? fx : ex / en;
  float oy = proto_zero ? fy : ey / en;
  if (!(n > 0.0f)) { ox = p.x; oy = p.y; }

  *reinterpret_cast<float2*>(out + (size_t)c * 128 + lane * 2) = make_float2(ox, oy);
}

extern "C" void kernel_launch(void* const* d_in, const int* in_sizes, int n_in,
                              void* d_out, int out_size, void* d_ws, size_t ws_size,
                              hipStream_t stream) {
  const float* feat = (const float*)d_in[0];
  const int* labels = (const int*)d_in[1];
  const float* proto = (const float*)d_in[2];
  float* out = (float*)d_out;

  const int N = in_sizes[1];
  const int D = in_sizes[0] / N;   // 128
  const int C = in_sizes[2] / D;   // 1000
  (void)D;

  // ws layout: idx[C*CAP] | cursor[C] (ints) | segp[HSPLIT*C*128] (float)
  int* idx = (int*)d_ws;
  int* cursor = idx + (size_t)C * CAP;
  float* segp = (float*)(cursor + C);

  (void)hipMemsetAsync(cursor, 0, (size_t)C * sizeof(int), stream);

  const int sblk = (N + SWIN - 1) / SWIN;
  scatter_kernel<<<sblk, 1024, 0, stream>>>(labels, N, C, cursor, idx);
  class_reduce_kernel<<<HSPLIT * C, 256, 0, stream>>>(feat, idx, cursor, segp, C);
  finalize_kernel<<<(C + 3) / 4, 256, 0, stream>>>(segp, cursor, proto, out, C);
}

// Round 8
// 125.750 us; speedup vs baseline: 1.1002x; 1.1002x over previous
//
#include <hip/hip_runtime.h>

#define EPSN 1e-12f
#define MOM 0.9f
#define MAXC 1024   // C=1000 fits
#define CAP 8192    // per-class bucket capacity (true max ~1150 for this input)
#define SWIN 4096   // rows per scatter block
#define HSPLIT 4    // class_reduce blocks per class

typedef float floatx4 __attribute__((ext_vector_type(4)));

// ---------------- K1: fused scatter (count -> reserve -> rank+write) -------
// Bucketed layout idx[c*CAP + pos]; cursor[c] ends equal to the class count.
// NOTE: idx stores must be REGULAR (cached) stores — nontemporal scattered
// 4B stores bypass L2 and regressed R7 by ~10us (HBM sector RMW + lost
// L2 residency for class_reduce's idx reads).
__global__ __launch_bounds__(1024) void scatter_kernel(
    const int* __restrict__ labels, int N, int C, int* __restrict__ cursor,
    int* __restrict__ idx) {
  __shared__ int llab[SWIN];    // window labels (read labels once)
  __shared__ int lcnt[MAXC];    // per-block class count, then rank counter
  __shared__ int lbase[MAXC];   // reserved global base per class
  const int s = blockIdx.x * SWIN;
  const int e = min(s + SWIN, N);
  const int nw = e - s;

  for (int i = threadIdx.x; i < C; i += blockDim.x) { lcnt[i] = 0; }
  __syncthreads();
  for (int i = threadIdx.x; i < nw; i += blockDim.x) {
    const int lab = labels[s + i];
    llab[i] = lab;
    atomicAdd(&lcnt[lab], 1);
  }
  __syncthreads();
  for (int i = threadIdx.x; i < C; i += blockDim.x) {
    const int k = lcnt[i];
    lbase[i] = k ? atomicAdd(&cursor[i], k) : 0;
    lcnt[i] = 0;   // reuse as rank counter
  }
  __syncthreads();
  for (int i = threadIdx.x; i < nw; i += blockDim.x) {
    const int lab = llab[i];
    const int r = atomicAdd(&lcnt[lab], 1);
    idx[lab * CAP + lbase[lab] + r] = s + i;
  }
}

// ---------------- K2: per-class gather + normalize + reduce ----------------
// HSPLIT blocks per class (one per quarter), 4 waves per block. Row layout:
// 16 lanes x float8 -> 4 rows per wave-instruction; one 4-level shuffle
// round reduces 4 row-norms at once. Unmasked main loop + masked tail.
__global__ __launch_bounds__(256) void class_reduce_kernel(
    const float* __restrict__ feat, const int* __restrict__ idx,
    const int* __restrict__ cnt, float* __restrict__ segp, int C) {
  __shared__ float part[4][128];
  const int c = blockIdx.x >> 2;
  const int h = blockIdx.x & 3;
  const int w = threadIdx.x >> 6;
  const int lane = threadIdx.x & 63;
  const int g = lane >> 4;     // row-group within wave (0..3)
  const int k = lane & 15;     // lane within group -> cols k*8..k*8+7
  const int n = cnt[c];
  const int per = (n + HSPLIT - 1) / HSPLIT;
  const int start = h * per;
  const int nh = max(0, min(per, n - start));
  const int beg = c * CAP + start;

  float acc[8];
  #pragma unroll
  for (int j = 0; j < 8; ++j) acc[j] = 0.f;

  const float* fbase = feat + (size_t)k * 8;
  const int tid16 = w * 4 + g;   // 0..15

  int base = 0;
  // ---- main loop: all 64 rows of the window valid, no masks ----
  for (; base + 63 < nh; base += 64) {
    const int j0 = base + tid16;
    int ri[4];
    #pragma unroll
    for (int u = 0; u < 4; ++u) ri[u] = idx[beg + j0 + u * 16];
    floatx4 a[4], b[4];
    #pragma unroll
    for (int u = 0; u < 4; ++u) {
      const float* p = fbase + (size_t)ri[u] * 128;
      a[u] = __builtin_nontemporal_load(reinterpret_cast<const floatx4*>(p));
      b[u] = __builtin_nontemporal_load(reinterpret_cast<const floatx4*>(p) + 1);
    }
    float sq[4];
    #pragma unroll
    for (int u = 0; u < 4; ++u) {
      sq[u] = a[u].x * a[u].x + a[u].y * a[u].y + a[u].z * a[u].z + a[u].w * a[u].w +
              b[u].x * b[u].x + b[u].y * b[u].y + b[u].z * b[u].z + b[u].w * b[u].w;
    }
    #pragma unroll
    for (int m = 1; m <= 8; m <<= 1) {
      #pragma unroll
      for (int u = 0; u < 4; ++u) sq[u] += __shfl_xor(sq[u], m);
    }
    #pragma unroll
    for (int u = 0; u < 4; ++u) {
      const float inv = 1.0f / fmaxf(sqrtf(sq[u]), EPSN);
      acc[0] += a[u].x * inv; acc[1] += a[u].y * inv;
      acc[2] += a[u].z * inv; acc[3] += a[u].w * inv;
      acc[4] += b[u].x * inv; acc[5] += b[u].y * inv;
      acc[6] += b[u].z * inv; acc[7] += b[u].w * inv;
    }
  }
  // ---- masked tail (at most one iteration) ----
  if (base < nh) {
    const int j0 = base + tid16;
    bool vm[4]; int ri[4];
    #pragma unroll
    for (int u = 0; u < 4; ++u) {
      const int jj = j0 + u * 16;
      vm[u] = jj < nh;
      ri[u] = idx[beg + (vm[u] ? jj : base)];
    }
    floatx4 a[4], b[4];
    #pragma unroll
    for (int u = 0; u < 4; ++u) {
      const float* p = fbase + (size_t)ri[u] * 128;
      a[u] = __builtin_nontemporal_load(reinterpret_cast<const floatx4*>(p));
      b[u] = __builtin_nontemporal_load(reinterpret_cast<const floatx4*>(p) + 1);
      if (!vm[u]) { a[u] = (floatx4)(0.f); b[u] = (floatx4)(0.f); }
    }
    float sq[4];
    #pragma unroll
    for (int u = 0; u < 4; ++u) {
      sq[u] = a[u].x * a[u].x + a[u].y * a[u].y + a[u].z * a[u].z + a[u].w * a[u].w +
              b[u].x * b[u].x + b[u].y * b[u].y + b[u].z * b[u].z + b[u].w * b[u].w;
    }
    #pragma unroll
    for (int m = 1; m <= 8; m <<= 1) {
      #pragma unroll
      for (int u = 0; u < 4; ++u) sq[u] += __shfl_xor(sq[u], m);
    }
    #pragma unroll
    for (int u = 0; u < 4; ++u) {
      const float inv = 1.0f / fmaxf(sqrtf(sq[u]), EPSN);
      acc[0] += a[u].x * inv; acc[1] += a[u].y * inv;
      acc[2] += a[u].z * inv; acc[3] += a[u].w * inv;
      acc[4] += b[u].x * inv; acc[5] += b[u].y * inv;
      acc[6] += b[u].z * inv; acc[7] += b[u].w * inv;
    }
  }

  // combine the 4 row-groups (they accumulate the same 128 columns)
  #pragma unroll
  for (int j = 0; j < 8; ++j) {
    acc[j] += __shfl_xor(acc[j], 16);
    acc[j] += __shfl_xor(acc[j], 32);
  }
  if (g == 0) {
    #pragma unroll
    for (int j = 0; j < 8; ++j) part[w][k * 8 + j] = acc[j];
  }
  __syncthreads();
  if (threadIdx.x < 128) {
    const float sTot = part[0][threadIdx.x] + part[1][threadIdx.x] +
                       part[2][threadIdx.x] + part[3][threadIdx.x];
    segp[((size_t)h * C + c) * 128 + threadIdx.x] = sTot;
  }
}

// ---------------- K3: finalize (wave per class) ----------------------------
__global__ __launch_bounds__(256) void finalize_kernel(
    const float* __restrict__ segp, const int* __restrict__ cnt,
    const float* __restrict__ proto, float* __restrict__ out, int C) {
  int wid = threadIdx.x >> 6;
  int lane = threadIdx.x & 63;
  int c = blockIdx.x * (blockDim.x >> 6) + wid;
  if (c >= C) return;

  const float n = (float)cnt[c];
  float sx = 0.f, sy = 0.f;
  #pragma unroll
  for (int h = 0; h < HSPLIT; ++h) {
    const float2 s0 = *reinterpret_cast<const float2*>(
        segp + ((size_t)h * C + c) * 128 + lane * 2);
    sx += s0.x; sy += s0.y;
  }
  const float2 p = *reinterpret_cast<const float2*>(proto + (size_t)c * 128 + lane * 2);

  const float inv_c = 1.0f / fmaxf(n, 1.0f);
  const float mx = sx * inv_c, my = sy * inv_c;

  float ss = mx * mx + my * my;   // for l2norm(feat_mean)
  float ps = p.x + p.y;           // elementwise sum of prototype row
  #pragma unroll
  for (int m = 32; m > 0; m >>= 1) {
    ss += __shfl_xor(ss, m);
    ps += __shfl_xor(ps, m);
  }
  const float fnorm = fmaxf(sqrtf(ss), EPSN);
  const float fx = mx / fnorm, fy = my / fnorm;

  const float ex = MOM * p.x + (1.0f - MOM) * fx;
  const float ey = MOM * p.y + (1.0f - MOM) * fy;
  float es = ex * ex + ey * ey;
  #pragma unroll
  for (int m = 32; m > 0; m >>= 1) es += __shfl_xor(es, m);
  const float en = fmaxf(sqrtf(es), EPSN);

  const bool proto_zero = (ps == 0.0f);
  float ox = proto_zero ? fx : ex / en;
  float oy = proto_zero ? fy : ey / en;
  if (!(n > 0.0f)) { ox = p.x; oy = p.y; }

  *reinterpret_cast<float2*>(out + (size_t)c * 128 + lane * 2) = make_float2(ox, oy);
}

extern "C" void kernel_launch(void* const* d_in, const int* in_sizes, int n_in,
                              void* d_out, int out_size, void* d_ws, size_t ws_size,
                              hipStream_t stream) {
  const float* feat = (const float*)d_in[0];
  const int* labels = (const int*)d_in[1];
  const float* proto = (const float*)d_in[2];
  float* out = (float*)d_out;

  const int N = in_sizes[1];
  const int D = in_sizes[0] / N;   // 128
  const int C = in_sizes[2] / D;   // 1000
  (void)D;

  // ws layout: idx[C*CAP] | cursor[C] (ints) | segp[HSPLIT*C*128] (float)
  int* idx = (int*)d_ws;
  int* cursor = idx + (size_t)C * CAP;
  float* segp = (float*)(cursor + C);

  (void)hipMemsetAsync(cursor, 0, (size_t)C * sizeof(int), stream);

  const int sblk = (N + SWIN - 1) / SWIN;
  scatter_kernel<<<sblk, 1024, 0, stream>>>(labels, N, C, cursor, idx);
  class_reduce_kernel<<<HSPLIT * C, 256, 0, stream>>>(feat, idx, cursor, segp, C);
  finalize_kernel<<<(C + 3) / 4, 256, 0, stream>>>(segp, cursor, proto, out, C);
}

// Round 9
// 113.710 us; speedup vs baseline: 1.2167x; 1.1059x over previous
//
#include <hip/hip_runtime.h>

#define EPSN 1e-12f
#define MOM 0.9f
#define MAXC 1024   // C=1000 fits
#define CAP 8192    // per-class bucket capacity (true max ~1150 for this input)
#define SWIN 4096   // rows per scatter block
#define HSPLIT 4    // class_reduce blocks per class

typedef float floatx4 __attribute__((ext_vector_type(4)));

// ---------------- K1: fused scatter (count -> reserve -> rank+write) -------
// Bucketed layout idx[c*CAP + pos]; cursor[c] ends equal to the class count.
// NOTE: idx stores must be REGULAR (cached) stores — nontemporal scattered
// 4B stores bypass L2 and regressed R7 by ~10us.
__global__ __launch_bounds__(1024) void scatter_kernel(
    const int* __restrict__ labels, int N, int C, int* __restrict__ cursor,
    int* __restrict__ idx) {
  __shared__ int llab[SWIN];    // window labels (read labels once)
  __shared__ int lcnt[MAXC];    // per-block class count, then rank counter
  __shared__ int lbase[MAXC];   // reserved global base per class
  const int s = blockIdx.x * SWIN;
  const int e = min(s + SWIN, N);
  const int nw = e - s;

  for (int i = threadIdx.x; i < C; i += blockDim.x) { lcnt[i] = 0; }
  __syncthreads();
  for (int i = threadIdx.x; i < nw; i += blockDim.x) {
    const int lab = labels[s + i];
    llab[i] = lab;
    atomicAdd(&lcnt[lab], 1);
  }
  __syncthreads();
  for (int i = threadIdx.x; i < C; i += blockDim.x) {
    const int k = lcnt[i];
    lbase[i] = k ? atomicAdd(&cursor[i], k) : 0;
    lcnt[i] = 0;   // reuse as rank counter
  }
  __syncthreads();
  for (int i = threadIdx.x; i < nw; i += blockDim.x) {
    const int lab = llab[i];
    const int r = atomicAdd(&lcnt[lab], 1);
    idx[lab * CAP + lbase[lab] + r] = s + i;
  }
}

// ---------------- K2: per-class gather + normalize + reduce ----------------
// HSPLIT blocks per class, 4 waves per block. Row layout: 32 lanes x float4
// -> each row is ONE contiguous 512B segment per wave-instruction (longer
// DRAM bursts than the previous 2x256B split). 2 row-groups/wave, unroll 8
// -> 16 rows (8KB) in flight per wave. Unmasked main loop + masked tail.
__global__ __launch_bounds__(256) void class_reduce_kernel(
    const float* __restrict__ feat, const int* __restrict__ idx,
    const int* __restrict__ cnt, float* __restrict__ segp, int C) {
  __shared__ float part[4][128];
  const int c = blockIdx.x >> 2;
  const int h = blockIdx.x & 3;
  const int w = threadIdx.x >> 6;
  const int lane = threadIdx.x & 63;
  const int g = lane >> 5;     // row-group within wave (0..1)
  const int k = lane & 31;     // lane within group -> cols k*4..k*4+3
  const int n = cnt[c];
  const int per = (n + HSPLIT - 1) / HSPLIT;
  const int start = h * per;
  const int nh = max(0, min(per, n - start));
  const int beg = c * CAP + start;

  float acc[4] = {0.f, 0.f, 0.f, 0.f};

  const float* fbase = feat + (size_t)k * 4;

  int base = 0;
  // ---- main loop: all 64 rows of the window valid, no masks ----
  for (; base + 63 < nh; base += 64) {
    const int j0 = base + w * 16 + g;   // rows j0 + u*2, u=0..7
    int ri[8];
    #pragma unroll
    for (int u = 0; u < 8; ++u) ri[u] = idx[beg + j0 + u * 2];
    floatx4 a[8];
    #pragma unroll
    for (int u = 0; u < 8; ++u)
      a[u] = __builtin_nontemporal_load(
          reinterpret_cast<const floatx4*>(fbase + (size_t)ri[u] * 128));
    float sq[8];
    #pragma unroll
    for (int u = 0; u < 8; ++u)
      sq[u] = a[u].x * a[u].x + a[u].y * a[u].y + a[u].z * a[u].z + a[u].w * a[u].w;
    #pragma unroll
    for (int m = 1; m <= 16; m <<= 1) {
      #pragma unroll
      for (int u = 0; u < 8; ++u) sq[u] += __shfl_xor(sq[u], m);
    }
    #pragma unroll
    for (int u = 0; u < 8; ++u) {
      const float inv = 1.0f / fmaxf(sqrtf(sq[u]), EPSN);
      acc[0] += a[u].x * inv; acc[1] += a[u].y * inv;
      acc[2] += a[u].z * inv; acc[3] += a[u].w * inv;
    }
  }
  // ---- masked tail (at most one iteration) ----
  if (base < nh) {
    const int j0 = base + w * 16 + g;
    bool vm[8]; int ri[8];
    #pragma unroll
    for (int u = 0; u < 8; ++u) {
      const int jj = j0 + u * 2;
      vm[u] = jj < nh;
      ri[u] = idx[beg + (vm[u] ? jj : base)];
    }
    floatx4 a[8];
    #pragma unroll
    for (int u = 0; u < 8; ++u) {
      a[u] = __builtin_nontemporal_load(
          reinterpret_cast<const floatx4*>(fbase + (size_t)ri[u] * 128));
      if (!vm[u]) a[u] = (floatx4)(0.f);
    }
    float sq[8];
    #pragma unroll
    for (int u = 0; u < 8; ++u)
      sq[u] = a[u].x * a[u].x + a[u].y * a[u].y + a[u].z * a[u].z + a[u].w * a[u].w;
    #pragma unroll
    for (int m = 1; m <= 16; m <<= 1) {
      #pragma unroll
      for (int u = 0; u < 8; ++u) sq[u] += __shfl_xor(sq[u], m);
    }
    #pragma unroll
    for (int u = 0; u < 8; ++u) {
      const float inv = 1.0f / fmaxf(sqrtf(sq[u]), EPSN);
      acc[0] += a[u].x * inv; acc[1] += a[u].y * inv;
      acc[2] += a[u].z * inv; acc[3] += a[u].w * inv;
    }
  }

  // combine the 2 row-groups (they accumulate the same 128 columns)
  #pragma unroll
  for (int j = 0; j < 4; ++j) acc[j] += __shfl_xor(acc[j], 32);
  if (g == 0) {
    #pragma unroll
    for (int j = 0; j < 4; ++j) part[w][k * 4 + j] = acc[j];
  }
  __syncthreads();
  if (threadIdx.x < 128) {
    const float sTot = part[0][threadIdx.x] + part[1][threadIdx.x] +
                       part[2][threadIdx.x] + part[3][threadIdx.x];
    segp[((size_t)h * C + c) * 128 + threadIdx.x] = sTot;
  }
}

// ---------------- K3: finalize (wave per class) ----------------------------
__global__ __launch_bounds__(256) void finalize_kernel(
    const float* __restrict__ segp, const int* __restrict__ cnt,
    const float* __restrict__ proto, float* __restrict__ out, int C) {
  int wid = threadIdx.x >> 6;
  int lane = threadIdx.x & 63;
  int c = blockIdx.x * (blockDim.x >> 6) + wid;
  if (c >= C) return;

  const float n = (float)cnt[c];
  float sx = 0.f, sy = 0.f;
  #pragma unroll
  for (int h = 0; h < HSPLIT; ++h) {
    const float2 s0 = *reinterpret_cast<const float2*>(
        segp + ((size_t)h * C + c) * 128 + lane * 2);
    sx += s0.x; sy += s0.y;
  }
  const float2 p = *reinterpret_cast<const float2*>(proto + (size_t)c * 128 + lane * 2);

  const float inv_c = 1.0f / fmaxf(n, 1.0f);
  const float mx = sx * inv_c, my = sy * inv_c;

  float ss = mx * mx + my * my;   // for l2norm(feat_mean)
  float ps = p.x + p.y;           // elementwise sum of prototype row
  #pragma unroll
  for (int m = 32; m > 0; m >>= 1) {
    ss += __shfl_xor(ss, m);
    ps += __shfl_xor(ps, m);
  }
  const float fnorm = fmaxf(sqrtf(ss), EPSN);
  const float fx = mx / fnorm, fy = my / fnorm;

  const float ex = MOM * p.x + (1.0f - MOM) * fx;
  const float ey = MOM * p.y + (1.0f - MOM) * fy;
  float es = ex * ex + ey * ey;
  #pragma unroll
  for (int m = 32; m > 0; m >>= 1) es += __shfl_xor(es, m);
  const float en = fmaxf(sqrtf(es), EPSN);

  const bool proto_zero = (ps == 0.0f);
  float ox = proto_zero ? fx : ex / en;
  float oy = proto_zero ? fy : ey / en;
  if (!(n > 0.0f)) { ox = p.x; oy = p.y; }

  *reinterpret_cast<float2*>(out + (size_t)c * 128 + lane * 2) = make_float2(ox, oy);
}

extern "C" void kernel_launch(void* const* d_in, const int* in_sizes, int n_in,
                              void* d_out, int out_size, void* d_ws, size_t ws_size,
                              hipStream_t stream) {
  const float* feat = (const float*)d_in[0];
  const int* labels = (const int*)d_in[1];
  const float* proto = (const float*)d_in[2];
  float* out = (float*)d_out;

  const int N = in_sizes[1];
  const int D = in_sizes[0] / N;   // 128
  const int C = in_sizes[2] / D;   // 1000
  (void)D;

  // ws layout: idx[C*CAP] | cursor[C] (ints) | segp[HSPLIT*C*128] (float)
  int* idx = (int*)d_ws;
  int* cursor = idx + (size_t)C * CAP;
  float* segp = (float*)(cursor + C);

  (void)hipMemsetAsync(cursor, 0, (size_t)C * sizeof(int), stream);

  const int sblk = (N + SWIN - 1) / SWIN;
  scatter_kernel<<<sblk, 1024, 0, stream>>>(labels, N, C, cursor, idx);
  class_reduce_kernel<<<HSPLIT * C, 256, 0, stream>>>(feat, idx, cursor, segp, C);
  finalize_kernel<<<(C + 3) / 4, 256, 0, stream>>>(segp, cursor, proto, out, C);
}